// Round 15
// baseline (1501.507 us; speedup 1.0000x reference)
//
#include <hip/hip_runtime.h>

#define HW 196
#define WIDTH 14
#define T_STEPS 32
#define KC 64      // centers / GRU channels
#define DD 512     // reduced dim
#define CIN 1024
#define NFR 256    // B*T
#define NB 8       // videos
#define NCOL (NFR * HW)   // 50176

using f16x8 = __attribute__((ext_vector_type(8))) _Float16;
using f16x4 = __attribute__((ext_vector_type(4))) _Float16;
using f32x4 = __attribute__((ext_vector_type(4))) float;
using f32x16 = __attribute__((ext_vector_type(16))) float;

__device__ __forceinline__ void gload_lds16(const void* g, void* l) {
  __builtin_amdgcn_global_load_lds(
      (const __attribute__((address_space(1))) void*)g,
      (__attribute__((address_space(3))) void*)l, 16, 0, 0);
}

// fast sigmoid / tanh: v_exp_f32 + v_rcp_f32 (validated rounds 7-13).
__device__ __forceinline__ float sigf(float x) {
  return __builtin_amdgcn_rcpf(1.0f + __expf(-x));
}
__device__ __forceinline__ float tanhfast(float x) {
  float e = __expf(2.0f * x);
  return 1.0f - 2.0f * __builtin_amdgcn_rcpf(e + 1.0f);
}

// ---------------------------------------------------------------------------
// f32 -> f16 elementwise convert (weights).
// ---------------------------------------------------------------------------
__global__ __launch_bounds__(256)
void cvt_f16(const float* __restrict__ src, _Float16* __restrict__ dst, int nelem) {
  int i = (blockIdx.x * 256 + threadIdx.x) * 4;
  if (i < nelem) {
    float4 v = *reinterpret_cast<const float4*>(src + i);
    f16x4 o;
    o[0] = (_Float16)v.x; o[1] = (_Float16)v.y;
    o[2] = (_Float16)v.z; o[3] = (_Float16)v.w;
    *reinterpret_cast<f16x4*>(dst + i) = o;
  }
}

// ---------------------------------------------------------------------------
// Transpose-convert x: (n, c, p) f32 -> xh[(n*196+p)][c] f16.
// ---------------------------------------------------------------------------
__global__ __launch_bounds__(256)
void transpose_x(const float* __restrict__ x, _Float16* __restrict__ xh) {
  __shared__ float tile[64][197];
  const int tid = threadIdx.x;
  const int w = tid >> 6, lane = tid & 63;
  const int n = blockIdx.y;
  const int c0 = blockIdx.x * 64;
  const float* src = x + ((size_t)n * CIN + c0) * HW;
  for (int rr = 0; rr < 16; ++rr) {
    int c = w * 16 + rr;
    if (lane < 49) {
      float4 v = *reinterpret_cast<const float4*>(src + (size_t)c * HW + lane * 4);
      tile[c][lane * 4 + 0] = v.x; tile[c][lane * 4 + 1] = v.y;
      tile[c][lane * 4 + 2] = v.z; tile[c][lane * 4 + 3] = v.w;
    }
  }
  __syncthreads();
  _Float16* dst = xh + (size_t)n * HW * CIN + c0;
  #pragma unroll
  for (int pass = 0; pass < 13; ++pass) {
    int p = (tid >> 4) + pass * 16;
    int cg = (tid & 15) * 4;
    if (p < HW) {
      f16x4 v;
      #pragma unroll
      for (int j = 0; j < 4; ++j) v[j] = (_Float16)tile[cg + j][p];
      *reinterpret_cast<f16x4*>(dst + (size_t)p * CIN + cg) = v;
    }
  }
}

// ---------------------------------------------------------------------------
// f16 MFMA GEMM (validated rounds 4-13).
// ---------------------------------------------------------------------------
template<int BM, int NMT, bool WT>
__global__ __launch_bounds__(256)
void gemm16(const _Float16* __restrict__ A, const _Float16* __restrict__ Bmat,
            const float* __restrict__ bias, float* __restrict__ outC,
            _Float16* __restrict__ outT, int M, int K) {
  constexpr int MF = BM / 32;
  union Smem {
    struct { _Float16 a[BM * 64]; _Float16 b[128 * 64]; } s;
    _Float16 t[WT ? 128 * 132 : 1];
  };
  __shared__ Smem u;

  const int tid = threadIdx.x;
  const int lane = tid & 63;
  const int w = tid >> 6;
  const int wm = w >> 1, wn = w & 1;
  const int l16 = lane & 15, lhi = lane >> 4;
  const int srow = lane >> 3, sslot = lane & 7;
  const int swz = (sslot ^ srow) << 4;
  const int nct = gridDim.x / NMT;
  const int mt = blockIdx.x / nct;
  const int ct = blockIdx.x - mt * nct;
  const int m0 = mt * BM;
  const int col0 = ct * 128;

  f32x4 acc[MF][4];
  #pragma unroll
  for (int i = 0; i < MF; ++i)
    #pragma unroll
    for (int f = 0; f < 4; ++f) acc[i][f] = {0.f, 0.f, 0.f, 0.f};

  for (int k0 = 0; k0 < K; k0 += 64) {
    #pragma unroll
    for (int s = 0; s < BM / 32; ++s) {
      int r = w * (BM / 4) + s * 8;
      gload_lds16((const char*)(A + (size_t)(m0 + r + srow) * K + k0) + swz,
                  (char*)u.s.a + r * 128);
    }
    #pragma unroll
    for (int s = 0; s < 4; ++s) {
      int r = w * 32 + s * 8;
      gload_lds16((const char*)(Bmat + (size_t)(col0 + r + srow) * K + k0) + swz,
                  (char*)u.s.b + r * 128);
    }
    __syncthreads();
    #pragma unroll
    for (int kk = 0; kk < 2; ++kk) {
      f16x8 af[MF];
      #pragma unroll
      for (int i = 0; i < MF; ++i) {
        int row = wm * (MF * 16) + i * 16 + l16;
        af[i] = *reinterpret_cast<const f16x8*>(
            (const char*)u.s.a + row * 128 + ((kk * 64 + lhi * 16) ^ ((row & 7) << 4)));
      }
      #pragma unroll
      for (int f = 0; f < 4; ++f) {
        int row = wn * 64 + f * 16 + l16;
        f16x8 bf = *reinterpret_cast<const f16x8*>(
            (const char*)u.s.b + row * 128 + ((kk * 64 + lhi * 16) ^ ((row & 7) << 4)));
        #pragma unroll
        for (int i = 0; i < MF; ++i)
          acc[i][f] = __builtin_amdgcn_mfma_f32_16x16x32_f16(af[i], bf, acc[i][f], 0, 0, 0);
      }
    }
    __syncthreads();
  }

  if constexpr (!WT) {
    #pragma unroll
    for (int i = 0; i < MF; ++i) {
      int m = m0 + wm * (MF * 16) + i * 16 + lhi * 4;
      float b0 = bias[m], b1 = bias[m + 1], b2 = bias[m + 2], b3 = bias[m + 3];
      #pragma unroll
      for (int f = 0; f < 4; ++f) {
        int col = col0 + wn * 64 + f * 16 + l16;
        float4 o = {acc[i][f][0] + b0, acc[i][f][1] + b1,
                    acc[i][f][2] + b2, acc[i][f][3] + b3};
        *reinterpret_cast<float4*>(outC + (size_t)col * M + m) = o;
      }
    }
  } else {
    #pragma unroll
    for (int i = 0; i < MF; ++i) {
      int ml = wm * (MF * 16) + i * 16 + lhi * 4;
      int m = m0 + ml;
      float b0 = bias[m], b1 = bias[m + 1], b2 = bias[m + 2], b3 = bias[m + 3];
      #pragma unroll
      for (int f = 0; f < 4; ++f) {
        int cl = wn * 64 + f * 16 + l16;
        f16x4 v;
        v[0] = (_Float16)(acc[i][f][0] + b0);
        v[1] = (_Float16)(acc[i][f][1] + b1);
        v[2] = (_Float16)(acc[i][f][2] + b2);
        v[3] = (_Float16)(acc[i][f][3] + b3);
        *reinterpret_cast<f16x4*>((char*)u.t + cl * 264 + ml * 2) = v;
      }
    }
    __syncthreads();
    #pragma unroll
    for (int pass = 0; pass < 16; ++pass) {
      int row = (tid >> 5) + pass * 8;
      int coff = (tid & 31) * 4;
      f16x4 v = *reinterpret_cast<const f16x4*>((const char*)u.t + row * 264 + coff * 2);
      *reinterpret_cast<f16x4*>(outT + (size_t)(col0 + row) * M + m0 + coff) = v;
    }
  }
}

// ---------------------------------------------------------------------------
// Pre-format U weights into 32x32x16 MFMA A-fragments.
// f = g*72 + mig*36 + kt  (g: 0=z,1=r,2=h; mig: 32-out-ch group; kt: 0..35).
// kt = tap*4 + chq; A[row=lane&31 -> out-ch mig*32+row][k = chq*16 +
// (lane>>5)*8 + j] where k indexes input ch; element = U[ch][ki][tap].
// ---------------------------------------------------------------------------
__global__ __launch_bounds__(64)
void format_u32(const float* __restrict__ Uz, const float* __restrict__ Ur,
                const float* __restrict__ Uh, _Float16* __restrict__ ufmt) {
  const int f = blockIdx.x;        // 0..215
  const int lane = threadIdx.x;
  const int g = f / 72;
  const int rem = f - g * 72;
  const int mig = rem / 36;
  const int kt = rem - mig * 36;
  const int tap = kt >> 2, chq = kt & 3;
  const float* U = (g == 0) ? Uz : (g == 1) ? Ur : Uh;
  const int ch = mig * 32 + (lane & 31);
  const int k0 = chq * 16 + (lane >> 5) * 8;
  f16x8 v;
  #pragma unroll
  for (int j = 0; j < 8; ++j)
    v[j] = (_Float16)U[(size_t)ch * 576 + (k0 + j) * 9 + tap];
  *reinterpret_cast<f16x8*>(ufmt + (size_t)f * 512 + lane * 8) = v;
}

// ---------------------------------------------------------------------------
// GRU v8: 32x32x16 MFMA. 16 blocks x 8 waves (512 thr, VGPR<=128 envelope).
// Wave = (mig = w&1 : 32-out-ch group, q = w>>1 : tiles {q, q+4} of 7
// 32-pixel tiles). Phase1: 36-kt loop, 1 bf read (b128) -> 2 MFMA (z,r) —
// exactly 2 af streams (round-11 rule). Phase2: 1 bf -> 1 MFMA (h).
// bf reads/CU/step: 1872 -> 1008. acc = f32x16; C/D: col=lane&31,
// row=(reg&3)+8*(reg>>2)+4*(lane>>5) (HW-verified m74/m101).
// z in LDS zbuf, h in LDS h32 (no persistent reg state - spill rule r7-9).
// 12 precomputed swizzled bases/tile (XOR indep of dy since 16%8==0).
// ---------------------------------------------------------------------------
__global__ __launch_bounds__(512, 2)
void gru32(const float* __restrict__ wxbc, const _Float16* __restrict__ ufmt,
           _Float16* __restrict__ a_f, _Float16* __restrict__ a_b) {
  __shared__ __align__(16) _Float16 hpad[256 * 64];   // 32KB padded h (swizzled)
  __shared__ __align__(16) _Float16 rhpad[256 * 64];  // 32KB padded r*h
  __shared__ __align__(16) _Float16 zbuf[HW * 64];    // 24.5KB z (swizzled)
  __shared__ __align__(16) float h32[HW * 68];        // 52KB fp32 h, padded rows

  const int tid = threadIdx.x;
  const int lane = tid & 63;
  const int w = tid >> 6;            // wave 0..7
  const int l31 = lane & 31, lhalf = lane >> 5;
  const int chain = blockIdx.x;
  const int b = chain >> 1, dir = chain & 1;
  const int mig = w & 1;             // 32-out-ch group
  const int q = w >> 1;              // tile slot 0..3
  const int kl16 = lhalf * 16;       // k-half byte offset within 32B ch-chunk

  for (int i = tid; i < 256 * 64; i += 512) { hpad[i] = (_Float16)0.f; rhpad[i] = (_Float16)0.f; }
  for (int i = tid; i < HW * 68; i += 512) h32[i] = 0.0f;
  __syncthreads();

  _Float16* adest = dir ? a_b : a_f;
  const char* hpadB = reinterpret_cast<const char*>(hpad);
  const char* rhpadB = reinterpret_cast<const char*>(rhpad);
  const _Float16* uf = ufmt + (size_t)lane * 8;
  const int fzz = mig * 36;          // z frag base
  const int fzr = 72 + mig * 36;     // r frag base
  const int fzh = 144 + mig * 36;    // h frag base

  for (int t = 0; t < T_STEPS; ++t) {
    const int tw = dir ? (T_STEPS - 1 - t) : t;
    const float* wtc = wxbc + (size_t)(b * T_STEPS + tw) * HW * KC;

    // ================= phase 1: z -> zbuf, r*h -> rhpad ====================
    for (int it = 0; it < 2; ++it) {
      const int nt = q + 4 * it;
      if (nt >= 7) break;
      const int p = nt * 32 + l31;
      const bool act = p < HW;
      const int pc = act ? p : (HW - 1);
      const int py = pc / 14, px_ = pc - py * 14;
      const int base0 = py * 16 + px_;
      const int tb = base0 * 128;
      int rbq[12];
      #pragma unroll
      for (int dx = 0; dx < 3; ++dx) {
        const int sw = ((base0 + dx) & 7) << 4;
        #pragma unroll
        for (int chq = 0; chq < 4; ++chq)
          rbq[dx * 4 + chq] = tb + dx * 128 + ((chq * 32 + kl16) ^ sw);
      }
      f32x16 accz = {}, accr = {};
      #pragma unroll
      for (int kt = 0; kt < 36; ++kt) {
        const int tap = kt >> 2, chq = kt & 3;
        const int dy = tap / 3, dx = tap - dy * 3;
        const f16x8 bf = *reinterpret_cast<const f16x8*>(
            hpadB + rbq[dx * 4 + chq] + dy * 2048);
        const f16x8 az = *reinterpret_cast<const f16x8*>(uf + (size_t)(fzz + kt) * 512);
        const f16x8 ar = *reinterpret_cast<const f16x8*>(uf + (size_t)(fzr + kt) * 512);
        accz = __builtin_amdgcn_mfma_f32_32x32x16_f16(az, bf, accz, 0, 0, 0);
        accr = __builtin_amdgcn_mfma_f32_32x32x16_f16(ar, bf, accr, 0, 0, 0);
      }
      if (act) {
        const int ppw = base0 + 17;
        #pragma unroll
        for (int rq = 0; rq < 4; ++rq) {
          const int ch = mig * 32 + rq * 8 + lhalf * 4;
          const float4 wt4 = *reinterpret_cast<const float4*>(wtc + (size_t)pc * KC + ch);
          const float4 hv = *reinterpret_cast<const float4*>(&h32[pc * 68 + ch]);
          const float wta[4] = {wt4.x, wt4.y, wt4.z, wt4.w};
          const float hva[4] = {hv.x, hv.y, hv.z, hv.w};
          f16x4 zw, rhw;
          #pragma unroll
          for (int jj = 0; jj < 4; ++jj) {
            float z = sigf(accz[rq * 4 + jj] + wta[jj]);
            float r = sigf(accr[rq * 4 + jj] + wta[jj]);
            zw[jj] = (_Float16)z;
            rhw[jj] = (_Float16)(r * hva[jj]);
          }
          *reinterpret_cast<f16x4*>(reinterpret_cast<char*>(zbuf) +
              p * 128 + ((ch * 2) ^ ((p & 7) << 4))) = zw;
          *reinterpret_cast<f16x4*>(reinterpret_cast<char*>(rhpad) +
              ppw * 128 + ((ch * 2) ^ ((ppw & 7) << 4))) = rhw;
        }
      }
    }
    __syncthreads();

    // ================= phase 2: hh = tanh(wt + conv(rh,Uh)); update h ======
    {
      _Float16* ad = adest + (size_t)(b * T_STEPS + tw) * HW * KC;
      for (int it = 0; it < 2; ++it) {
        const int nt = q + 4 * it;
        if (nt >= 7) break;
        const int p = nt * 32 + l31;
        const bool act = p < HW;
        const int pc = act ? p : (HW - 1);
        const int py = pc / 14, px_ = pc - py * 14;
        const int base0 = py * 16 + px_;
        const int tb = base0 * 128;
        int rbq[12];
        #pragma unroll
        for (int dx = 0; dx < 3; ++dx) {
          const int sw = ((base0 + dx) & 7) << 4;
          #pragma unroll
          for (int chq = 0; chq < 4; ++chq)
            rbq[dx * 4 + chq] = tb + dx * 128 + ((chq * 32 + kl16) ^ sw);
        }
        f32x16 acch = {};
        #pragma unroll
        for (int kt = 0; kt < 36; ++kt) {
          const int tap = kt >> 2, chq = kt & 3;
          const int dy = tap / 3, dx = tap - dy * 3;
          const f16x8 bf = *reinterpret_cast<const f16x8*>(
              rhpadB + rbq[dx * 4 + chq] + dy * 2048);
          const f16x8 ah = *reinterpret_cast<const f16x8*>(uf + (size_t)(fzh + kt) * 512);
          acch = __builtin_amdgcn_mfma_f32_32x32x16_f16(ah, bf, acch, 0, 0, 0);
        }
        if (act) {
          const int ppw = base0 + 17;
          #pragma unroll
          for (int rq = 0; rq < 4; ++rq) {
            const int ch = mig * 32 + rq * 8 + lhalf * 4;
            const float4 wt4 = *reinterpret_cast<const float4*>(wtc + (size_t)pc * KC + ch);
            const f16x4 zv = *reinterpret_cast<const f16x4*>(
                reinterpret_cast<const char*>(zbuf) + p * 128 + ((ch * 2) ^ ((p & 7) << 4)));
            const float4 hv = *reinterpret_cast<const float4*>(&h32[pc * 68 + ch]);
            const float wta[4] = {wt4.x, wt4.y, wt4.z, wt4.w};
            const float hva[4] = {hv.x, hv.y, hv.z, hv.w};
            f16x4 hw;
            float hna[4];
            #pragma unroll
            for (int jj = 0; jj < 4; ++jj) {
              float hh = tanhfast(acch[rq * 4 + jj] + wta[jj]);
              float z = (float)zv[jj];
              float hn = hh + z * (hva[jj] - hh);   // (1-z)*hh + z*h
              hna[jj] = hn;
              hw[jj] = (_Float16)hn;
            }
            float4 hn4 = {hna[0], hna[1], hna[2], hna[3]};
            *reinterpret_cast<float4*>(&h32[pc * 68 + ch]) = hn4;
            *reinterpret_cast<f16x4*>(reinterpret_cast<char*>(hpad) +
                ppw * 128 + ((ch * 2) ^ ((ppw & 7) << 4))) = hw;
            *reinterpret_cast<f16x4*>(ad + (size_t)pc * KC + ch) = hw;
          }
        }
      }
    }
    __syncthreads();
  }
}

// ---------------------------------------------------------------------------
// softmax over K=64 per pixel-row; f16 in, f16 out (validated round 13).
// ---------------------------------------------------------------------------
__global__ __launch_bounds__(256)
void softmax_kernel(const _Float16* __restrict__ af, const _Float16* __restrict__ ab,
                    _Float16* __restrict__ out) {
  size_t idx = (size_t)blockIdx.x * 256 + threadIdx.x;   // 0..50175
  const _Float16* cf = af + idx * KC;
  const _Float16* cb = ab + idx * KC;
  _Float16* co = out + idx * KC;
  float v[KC];
  float mx = -3.4e38f;
  #pragma unroll
  for (int g = 0; g < 8; ++g) {
    f16x8 a = *reinterpret_cast<const f16x8*>(cf + g * 8);
    f16x8 bq = *reinterpret_cast<const f16x8*>(cb + g * 8);
    #pragma unroll
    for (int j = 0; j < 8; ++j) {
      float s = (float)a[j] + (float)bq[j];
      v[g * 8 + j] = s;
      mx = fmaxf(mx, s);
    }
  }
  float ssum = 0.0f;
  #pragma unroll
  for (int k = 0; k < KC; ++k) { v[k] = __expf(v[k] - mx); ssum += v[k]; }
  float inv = __builtin_amdgcn_rcpf(ssum);
  #pragma unroll
  for (int g = 0; g < 8; ++g) {
    f16x8 o;
    #pragma unroll
    for (int j = 0; j < 8; ++j) o[j] = (_Float16)(v[g * 8 + j] * inv);
    *reinterpret_cast<f16x8*>(co + g * 8) = o;
  }
}

// ---------------------------------------------------------------------------
// S[b][k] = sum over (t,p) of assign (f16 [n][p][k]). grid (8 seg, 8 b).
// ---------------------------------------------------------------------------
__global__ __launch_bounds__(256)
void sreduce_kernel(const _Float16* __restrict__ a, float* __restrict__ S) {
  __shared__ float red[4][64];
  const int seg = blockIdx.x, b = blockIdx.y, tid = threadIdx.x;
  const int k = tid & 63, rg = tid >> 6;
  const _Float16* base = a + (size_t)b * T_STEPS * HW * KC;
  float sum = 0.0f;
  for (int rr = seg * 784 + rg; rr < (seg + 1) * 784; rr += 4)
    sum += (float)base[(size_t)rr * KC + k];
  red[rg][k] = sum;
  __syncthreads();
  if (tid < 64) {
    float s = red[0][k] + red[1][k] + red[2][k] + red[3][k];
    atomicAdd(&S[b * KC + k], s);
  }
}

// ---------------------------------------------------------------------------
// VLAD GEMM partials (validated round 13). grid (8 d, 8 tc, 8 b).
// ---------------------------------------------------------------------------
__global__ __launch_bounds__(256)
void vlad_gemm_kernel(const _Float16* __restrict__ a, const _Float16* __restrict__ xrh,
                      float* __restrict__ Gpart) {
  __shared__ float sA[16][68];
  __shared__ float sX[16][68];
  const int tid = threadIdx.x;
  const int tx = tid & 15, ty = tid >> 4;
  const int d0 = blockIdx.x * 64;
  const int tc = blockIdx.y;
  const int b  = blockIdx.z;
  const int kk = tid & 63, pj = tid >> 6;
  float acc[4][4] = {};

  for (int tt = 0; tt < 4; ++tt) {
    int n = b * T_STEPS + tc * 4 + tt;
    const _Float16* an = a + (size_t)n * HW * KC;
    const _Float16* xn = xrh + (size_t)n * HW * DD;
    for (int p0 = 0; p0 < HW; p0 += 16) {
      __syncthreads();
      #pragma unroll
      for (int j = 0; j < 4; ++j) {
        int pl = pj * 4 + j;
        int p = p0 + pl;
        sA[pl][kk] = (p < HW) ? (float)an[(size_t)p * KC + kk] : 0.0f;
        sX[pl][kk] = (p < HW) ? (float)xn[(size_t)p * DD + d0 + kk] : 0.0f;
      }
      __syncthreads();
      #pragma unroll
      for (int pp = 0; pp < 16; ++pp) {
        float4 av = *reinterpret_cast<const float4*>(&sA[pp][ty * 4]);
        float4 xv = *reinterpret_cast<const float4*>(&sX[pp][tx * 4]);
        float aa[4] = {av.x, av.y, av.z, av.w};
        float xx[4] = {xv.x, xv.y, xv.z, xv.w};
        #pragma unroll
        for (int i = 0; i < 4; ++i)
          #pragma unroll
          for (int j = 0; j < 4; ++j)
            acc[i][j] += aa[i] * xx[j];
      }
    }
  }
  float* gp = Gpart + ((size_t)(tc * NB + b) * KC) * DD;
  #pragma unroll
  for (int i = 0; i < 4; ++i)
    #pragma unroll
    for (int j = 0; j < 4; ++j)
      gp[(ty * 4 + i) * DD + d0 + tx * 4 + j] = acc[i][j];
}

__global__ __launch_bounds__(256)
void finalize1_kernel(const float* __restrict__ Gpart, const float* __restrict__ S,
                      const float* __restrict__ centers, float* __restrict__ out,
                      float* __restrict__ bsum) {
  __shared__ float red[256];
  const int k = blockIdx.x, b = blockIdx.y, tid = threadIdx.x;
  const float sv = S[b * KC + k];
  float vals[2];
  float ss = 0.0f;
  #pragma unroll
  for (int r = 0; r < 2; ++r) {
    int d = tid + r * 256;
    float g = 0.0f;
    #pragma unroll
    for (int tc = 0; tc < 8; ++tc)
      g += Gpart[((size_t)(tc * NB + b) * KC + k) * DD + d];
    float v = g - sv * centers[k * DD + d];
    vals[r] = v; ss += v * v;
  }
  red[tid] = ss; __syncthreads();
  for (int st = 128; st > 0; st >>= 1) {
    if (tid < st) red[tid] += red[tid + st];
    __syncthreads();
  }
  float tot = red[0];
  float inv = 1.0f / fmaxf(sqrtf(tot), 1e-12f);
  #pragma unroll
  for (int r = 0; r < 2; ++r) {
    int d = tid + r * 256;
    out[(size_t)b * KC * DD + k * DD + d] = vals[r] * inv;
  }
  if (tid == 0) atomicAdd(&bsum[b], tot * inv * inv);
}

__global__ __launch_bounds__(256)
void finalize2_kernel(float* __restrict__ out, const float* __restrict__ bsum) {
  int idx = blockIdx.x * 256 + threadIdx.x;
  int b = idx >> 15;
  out[idx] = out[idx] / fmaxf(sqrtf(bsum[b]), 1e-12f);
}

// ---------------------------------------------------------------------------
extern "C" void kernel_launch(void* const* d_in, const int* in_sizes, int n_in,
                              void* d_out, int out_size, void* d_ws, size_t ws_size,
                              hipStream_t stream) {
  const float* x       = (const float*)d_in[0];
  const float* redu_w  = (const float*)d_in[1];
  const float* redu_b  = (const float*)d_in[2];
  const float* share_w = (const float*)d_in[3];
  const float* share_b = (const float*)d_in[4];
  const float* Uz      = (const float*)d_in[5];
  const float* Ur      = (const float*)d_in[6];
  const float* Uh      = (const float*)d_in[7];
  const float* centers = (const float*)d_in[8];
  float* out = (float*)d_out;

  // workspace layout (unchanged footprint vs rounds 4-13, ~172 MB):
  float* wxbc = (float*)d_ws;                                // [col][64] f32 (12.85MB)
  _Float16* assignh = (_Float16*)wxbc;                       // f16 overlay (wxbc dead after GRU)
  _Float16* xh = (_Float16*)(wxbc + (size_t)NCOL * KC);      // [col][1024] f16 (102.8MB)
  _Float16* a_f = xh;                                        // overlay (xh dead after gemmA)
  _Float16* a_b = a_f + (size_t)NFR * HW * KC;
  float* Gpart = (float*)(a_b + (size_t)NFR * HW * KC);      // 8*NB*KC*DD f32 (8.4MB)
  _Float16* xrh = xh + (size_t)NCOL * CIN;                   // [col][512] f16 (51.4MB)
  float* S = (float*)(xrh + (size_t)NCOL * DD);              // 512
  float* bsum = S + 512;                                     // 8
  _Float16* ufmt = (_Float16*)(bsum + 8);                    // 216*512 f16
  _Float16* wh = ufmt + 216 * 512;
  _Float16* swh = wh + (size_t)DD * CIN;

  hipMemsetAsync(bsum, 0, NB * sizeof(float), stream);
  hipMemsetAsync(S, 0, 512 * sizeof(float), stream);

  cvt_f16<<<dim3(512), 256, 0, stream>>>(redu_w, wh, DD * CIN);
  cvt_f16<<<dim3(32), 256, 0, stream>>>(share_w, swh, KC * DD);
  format_u32<<<dim3(216), 64, 0, stream>>>(Uz, Ur, Uh, ufmt);
  transpose_x<<<dim3(16, 256), 256, 0, stream>>>(x, xh);

  // stage A: xrh[col][512] f16 = wh[512x1024] * xh^T
  gemm16<128, 4, true><<<dim3(392 * 4), 256, 0, stream>>>(
      wh, xh, redu_b, nullptr, xrh, DD, CIN);
  // stage B: wxbc[col][64] f32 = swh[64x512] * xrh^T
  gemm16<64, 1, false><<<dim3(392), 256, 0, stream>>>(
      swh, xrh, share_b, wxbc, nullptr, KC, DD);

  // GRU: 32x32x16 MFMA, 2x less LDS bf traffic, 2 af streams
  gru32<<<dim3(16), 512, 0, stream>>>(wxbc, ufmt, a_f, a_b);

  softmax_kernel<<<dim3(196), 256, 0, stream>>>(a_f, a_b, assignh);
  sreduce_kernel<<<dim3(8, 8), 256, 0, stream>>>(assignh, S);
  vlad_gemm_kernel<<<dim3(8, 8, 8), 256, 0, stream>>>(assignh, xrh, Gpart);
  finalize1_kernel<<<dim3(64, 8), 256, 0, stream>>>(Gpart, S, centers, out, bsum);
  finalize2_kernel<<<dim3(1024), 256, 0, stream>>>(out, bsum);
}

// Round 16
// 771.154 us; speedup vs baseline: 1.9471x; 1.9471x over previous
//
#include <hip/hip_runtime.h>

#define HW 196
#define WIDTH 14
#define T_STEPS 32
#define KC 64      // centers / GRU channels
#define DD 512     // reduced dim
#define CIN 1024
#define NFR 256    // B*T
#define NB 8       // videos
#define NCOL (NFR * HW)   // 50176

using f16x8 = __attribute__((ext_vector_type(8))) _Float16;
using f16x4 = __attribute__((ext_vector_type(4))) _Float16;
using f32x4 = __attribute__((ext_vector_type(4))) float;

__device__ __forceinline__ void gload_lds16(const void* g, void* l) {
  __builtin_amdgcn_global_load_lds(
      (const __attribute__((address_space(1))) void*)g,
      (__attribute__((address_space(3))) void*)l, 16, 0, 0);
}

// fast sigmoid / tanh: v_exp_f32 + v_rcp_f32 (validated rounds 7-13).
__device__ __forceinline__ float sigf(float x) {
  return __builtin_amdgcn_rcpf(1.0f + __expf(-x));
}
__device__ __forceinline__ float tanhfast(float x) {
  float e = __expf(2.0f * x);
  return 1.0f - 2.0f * __builtin_amdgcn_rcpf(e + 1.0f);
}

// ---------------------------------------------------------------------------
// f32 -> f16 elementwise convert (weights).
// ---------------------------------------------------------------------------
__global__ __launch_bounds__(256)
void cvt_f16(const float* __restrict__ src, _Float16* __restrict__ dst, int nelem) {
  int i = (blockIdx.x * 256 + threadIdx.x) * 4;
  if (i < nelem) {
    float4 v = *reinterpret_cast<const float4*>(src + i);
    f16x4 o;
    o[0] = (_Float16)v.x; o[1] = (_Float16)v.y;
    o[2] = (_Float16)v.z; o[3] = (_Float16)v.w;
    *reinterpret_cast<f16x4*>(dst + i) = o;
  }
}

// ---------------------------------------------------------------------------
// Transpose-convert x: (n, c, p) f32 -> xh[(n*196+p)][c] f16.
// ---------------------------------------------------------------------------
__global__ __launch_bounds__(256)
void transpose_x(const float* __restrict__ x, _Float16* __restrict__ xh) {
  __shared__ float tile[64][197];
  const int tid = threadIdx.x;
  const int w = tid >> 6, lane = tid & 63;
  const int n = blockIdx.y;
  const int c0 = blockIdx.x * 64;
  const float* src = x + ((size_t)n * CIN + c0) * HW;
  for (int rr = 0; rr < 16; ++rr) {
    int c = w * 16 + rr;
    if (lane < 49) {
      float4 v = *reinterpret_cast<const float4*>(src + (size_t)c * HW + lane * 4);
      tile[c][lane * 4 + 0] = v.x; tile[c][lane * 4 + 1] = v.y;
      tile[c][lane * 4 + 2] = v.z; tile[c][lane * 4 + 3] = v.w;
    }
  }
  __syncthreads();
  _Float16* dst = xh + (size_t)n * HW * CIN + c0;
  #pragma unroll
  for (int pass = 0; pass < 13; ++pass) {
    int p = (tid >> 4) + pass * 16;
    int cg = (tid & 15) * 4;
    if (p < HW) {
      f16x4 v;
      #pragma unroll
      for (int j = 0; j < 4; ++j) v[j] = (_Float16)tile[cg + j][p];
      *reinterpret_cast<f16x4*>(dst + (size_t)p * CIN + cg) = v;
    }
  }
}

// ---------------------------------------------------------------------------
// f16 MFMA GEMM (validated rounds 4-13).
// ---------------------------------------------------------------------------
template<int BM, int NMT, bool WT>
__global__ __launch_bounds__(256)
void gemm16(const _Float16* __restrict__ A, const _Float16* __restrict__ Bmat,
            const float* __restrict__ bias, float* __restrict__ outC,
            _Float16* __restrict__ outT, int M, int K) {
  constexpr int MF = BM / 32;
  union Smem {
    struct { _Float16 a[BM * 64]; _Float16 b[128 * 64]; } s;
    _Float16 t[WT ? 128 * 132 : 1];
  };
  __shared__ Smem u;

  const int tid = threadIdx.x;
  const int lane = tid & 63;
  const int w = tid >> 6;
  const int wm = w >> 1, wn = w & 1;
  const int l16 = lane & 15, lhi = lane >> 4;
  const int srow = lane >> 3, sslot = lane & 7;
  const int swz = (sslot ^ srow) << 4;
  const int nct = gridDim.x / NMT;
  const int mt = blockIdx.x / nct;
  const int ct = blockIdx.x - mt * nct;
  const int m0 = mt * BM;
  const int col0 = ct * 128;

  f32x4 acc[MF][4];
  #pragma unroll
  for (int i = 0; i < MF; ++i)
    #pragma unroll
    for (int f = 0; f < 4; ++f) acc[i][f] = {0.f, 0.f, 0.f, 0.f};

  for (int k0 = 0; k0 < K; k0 += 64) {
    #pragma unroll
    for (int s = 0; s < BM / 32; ++s) {
      int r = w * (BM / 4) + s * 8;
      gload_lds16((const char*)(A + (size_t)(m0 + r + srow) * K + k0) + swz,
                  (char*)u.s.a + r * 128);
    }
    #pragma unroll
    for (int s = 0; s < 4; ++s) {
      int r = w * 32 + s * 8;
      gload_lds16((const char*)(Bmat + (size_t)(col0 + r + srow) * K + k0) + swz,
                  (char*)u.s.b + r * 128);
    }
    __syncthreads();
    #pragma unroll
    for (int kk = 0; kk < 2; ++kk) {
      f16x8 af[MF];
      #pragma unroll
      for (int i = 0; i < MF; ++i) {
        int row = wm * (MF * 16) + i * 16 + l16;
        af[i] = *reinterpret_cast<const f16x8*>(
            (const char*)u.s.a + row * 128 + ((kk * 64 + lhi * 16) ^ ((row & 7) << 4)));
      }
      #pragma unroll
      for (int f = 0; f < 4; ++f) {
        int row = wn * 64 + f * 16 + l16;
        f16x8 bf = *reinterpret_cast<const f16x8*>(
            (const char*)u.s.b + row * 128 + ((kk * 64 + lhi * 16) ^ ((row & 7) << 4)));
        #pragma unroll
        for (int i = 0; i < MF; ++i)
          acc[i][f] = __builtin_amdgcn_mfma_f32_16x16x32_f16(af[i], bf, acc[i][f], 0, 0, 0);
      }
    }
    __syncthreads();
  }

  if constexpr (!WT) {
    #pragma unroll
    for (int i = 0; i < MF; ++i) {
      int m = m0 + wm * (MF * 16) + i * 16 + lhi * 4;
      float b0 = bias[m], b1 = bias[m + 1], b2 = bias[m + 2], b3 = bias[m + 3];
      #pragma unroll
      for (int f = 0; f < 4; ++f) {
        int col = col0 + wn * 64 + f * 16 + l16;
        float4 o = {acc[i][f][0] + b0, acc[i][f][1] + b1,
                    acc[i][f][2] + b2, acc[i][f][3] + b3};
        *reinterpret_cast<float4*>(outC + (size_t)col * M + m) = o;
      }
    }
  } else {
    #pragma unroll
    for (int i = 0; i < MF; ++i) {
      int ml = wm * (MF * 16) + i * 16 + lhi * 4;
      int m = m0 + ml;
      float b0 = bias[m], b1 = bias[m + 1], b2 = bias[m + 2], b3 = bias[m + 3];
      #pragma unroll
      for (int f = 0; f < 4; ++f) {
        int cl = wn * 64 + f * 16 + l16;
        f16x4 v;
        v[0] = (_Float16)(acc[i][f][0] + b0);
        v[1] = (_Float16)(acc[i][f][1] + b1);
        v[2] = (_Float16)(acc[i][f][2] + b2);
        v[3] = (_Float16)(acc[i][f][3] + b3);
        *reinterpret_cast<f16x4*>((char*)u.t + cl * 264 + ml * 2) = v;
      }
    }
    __syncthreads();
    #pragma unroll
    for (int pass = 0; pass < 16; ++pass) {
      int row = (tid >> 5) + pass * 8;
      int coff = (tid & 31) * 4;
      f16x4 v = *reinterpret_cast<const f16x4*>((const char*)u.t + row * 264 + coff * 2);
      *reinterpret_cast<f16x4*>(outT + (size_t)(col0 + row) * M + m0 + coff) = v;
    }
  }
}

// ---------------------------------------------------------------------------
// Pre-format U weights into 16x16x32 MFMA A-fragments (validated round 3).
// ---------------------------------------------------------------------------
__global__ __launch_bounds__(64)
void format_u(const float* __restrict__ Uz, const float* __restrict__ Ur,
              const float* __restrict__ Uh, _Float16* __restrict__ ufmt) {
  const int f = blockIdx.x;        // 0..215
  const int lane = threadIdx.x;
  const int l16 = lane & 15;
  const float* U;
  int ch, kt;
  if (f < 144) {
    int pair = f / 36, rem = f - pair * 36;
    int mi = rem / 18; kt = rem - mi * 18;
    U = (pair < 2) ? Uz : Ur;
    ch = (pair & 1) * 32 + mi * 16 + l16;
  } else {
    int g = f - 144;
    int pair = g / 36, rem = g - pair * 36;
    int mi = rem / 18; kt = rem - mi * 18;
    U = Uh;
    ch = pair * 32 + mi * 16 + l16;
  }
  const int tap = kt >> 1;
  const int k0 = (kt & 1) * 32 + (lane >> 4) * 8;
  f16x8 v;
  #pragma unroll
  for (int j = 0; j < 8; ++j)
    v[j] = (_Float16)U[(size_t)ch * 576 + (k0 + j) * 9 + tap];
  *reinterpret_cast<f16x8*>(ufmt + (size_t)f * 512 + lane * 8) = v;
}

// ---------------------------------------------------------------------------
// GRU (EXACT round-10/13 kernel, proven 443 us, best of 8 structural
// variants). Hard constraints established this session:
//  - 512-thr block (1024 thr -> 64-VGPR cap, catastrophic spill, r9)
//  - af fragment arrays HOISTED per phase, <=2 streams (inside-loop or >2
//    streams -> per-MFMA L2 stall, r11/r14)
//  - z/h state in LDS, not registers (persistent reg state -> spill, r7-9)
//  - 16x16x32 MFMA (32x32x16 doubles acc VGPRs -> spill + dep chains, r14)
// ---------------------------------------------------------------------------
__global__ __launch_bounds__(512, 2)
void gru_mfma8(const float* __restrict__ wxbc, const _Float16* __restrict__ ufmt,
               _Float16* __restrict__ a_f, _Float16* __restrict__ a_b) {
  __shared__ __align__(16) _Float16 hpad[256 * 64];   // 32KB padded h (swizzled)
  __shared__ __align__(16) _Float16 rhpad[256 * 64];  // 32KB padded r*h
  __shared__ __align__(16) _Float16 zbuf[208 * 64];   // 26.6KB z (swizzled)
  __shared__ __align__(16) float h32[HW * 68];        // 52KB fp32 h, padded rows

  const int tid = threadIdx.x;
  const int lane = tid & 63;
  const int w = tid >> 6;            // wave 0..7
  const int l16 = lane & 15, lhi = lane >> 4;
  const int chain = blockIdx.x;
  const int b = chain >> 1, dir = chain & 1;
  const int mi = w & 3;
  const int half = w >> 2;
  const int ntb = half * 7;          // base pixel-tile
  const int ntn = half ? 6 : 7;      // tiles owned
  const int ch0 = mi * 16 + lhi * 4;
  const int chlo = lhi * 16, chhi = 64 + lhi * 16;

  for (int i = tid; i < 256 * 64; i += 512) { hpad[i] = (_Float16)0.f; rhpad[i] = (_Float16)0.f; }
  for (int i = tid; i < HW * 68; i += 512) h32[i] = 0.0f;
  __syncthreads();

  _Float16* adest = dir ? a_b : a_f;
  const char* hpadB = reinterpret_cast<const char*>(hpad);
  const char* rhpadB = reinterpret_cast<const char*>(rhpad);
  const _Float16* uf = ufmt + (size_t)lane * 8;
  const int fz0 = (mi >> 1) * 36 + (mi & 1) * 18;

  for (int t = 0; t < T_STEPS; ++t) {
    const int tw = dir ? (T_STEPS - 1 - t) : t;
    const float* wtc = wxbc + (size_t)(b * T_STEPS + tw) * HW * KC;

    // ================= phase 1: z -> zbuf, r*h -> rhpad ====================
    {
      f16x8 afz[18], afr[18];
      #pragma unroll
      for (int kt = 0; kt < 18; ++kt) {
        afz[kt] = *reinterpret_cast<const f16x8*>(uf + (size_t)(fz0 + kt) * 512);
        afr[kt] = *reinterpret_cast<const f16x8*>(uf + (size_t)(fz0 + 72 + kt) * 512);
      }
      for (int i = 0; i < ntn; ++i) {
        const int nt = ntb + i;
        const int p = nt * 16 + l16;
        const bool act = p < HW;
        const int pc = act ? p : (HW - 1);
        const int py = pc / 14, px_ = pc - py * 14;
        const int base0 = py * 16 + px_;
        const int tb = base0 * 128;
        const int rb0 = tb +       (chlo ^ ((px_ & 7) << 4));
        const int rb1 = tb + 128 + (chlo ^ (((px_ + 1) & 7) << 4));
        const int rb2 = tb + 256 + (chlo ^ (((px_ + 2) & 7) << 4));
        const int rb3 = tb +       (chhi ^ ((px_ & 7) << 4));
        const int rb4 = tb + 128 + (chhi ^ (((px_ + 1) & 7) << 4));
        const int rb5 = tb + 256 + (chhi ^ (((px_ + 2) & 7) << 4));
        const float4 wt4 = *reinterpret_cast<const float4*>(wtc + (size_t)pc * KC + ch0);
        f32x4 az = {0.f, 0.f, 0.f, 0.f};
        f32x4 ar = {0.f, 0.f, 0.f, 0.f};
        #pragma unroll
        for (int kt = 0; kt < 18; ++kt) {
          const int tap = kt >> 1, dy = tap / 3, dx = tap - dy * 3;
          const int base = (kt & 1) ? (dx == 0 ? rb3 : dx == 1 ? rb4 : rb5)
                                    : (dx == 0 ? rb0 : dx == 1 ? rb1 : rb2);
          const f16x8 bf = *reinterpret_cast<const f16x8*>(hpadB + base + dy * 2048);
          az = __builtin_amdgcn_mfma_f32_16x16x32_f16(afz[kt], bf, az, 0, 0, 0);
          ar = __builtin_amdgcn_mfma_f32_16x16x32_f16(afr[kt], bf, ar, 0, 0, 0);
        }
        if (act) {
          const float wta[4] = {wt4.x, wt4.y, wt4.z, wt4.w};
          const float4 hv = *reinterpret_cast<const float4*>(&h32[pc * 68 + ch0]);
          const float hva[4] = {hv.x, hv.y, hv.z, hv.w};
          f16x4 zw, rhw;
          #pragma unroll
          for (int jj = 0; jj < 4; ++jj) {
            float z = sigf(az[jj] + wta[jj]);
            float r = sigf(ar[jj] + wta[jj]);
            zw[jj] = (_Float16)z;
            rhw[jj] = (_Float16)(r * hva[jj]);
          }
          *reinterpret_cast<f16x4*>(reinterpret_cast<char*>(zbuf) +
              p * 128 + ((ch0 * 2) ^ ((p & 7) << 4))) = zw;
          const int ppw = base0 + 17;
          *reinterpret_cast<f16x4*>(reinterpret_cast<char*>(rhpad) +
              ppw * 128 + ((ch0 * 2) ^ ((ppw & 7) << 4))) = rhw;
        }
      }
    }
    __syncthreads();

    // ================= phase 2: hh = tanh(wt + conv(rh,Uh)); update h ======
    {
      _Float16* ad = adest + (size_t)(b * T_STEPS + tw) * HW * KC;
      f16x8 afh[18];
      #pragma unroll
      for (int kt = 0; kt < 18; ++kt)
        afh[kt] = *reinterpret_cast<const f16x8*>(uf + (size_t)(144 + fz0 + kt) * 512);
      for (int i = 0; i < ntn; ++i) {
        const int nt = ntb + i;
        const int p = nt * 16 + l16;
        const bool act = p < HW;
        const int pc = act ? p : (HW - 1);
        const int py = pc / 14, px_ = pc - py * 14;
        const int base0 = py * 16 + px_;
        const int tb = base0 * 128;
        const int rb0 = tb +       (chlo ^ ((px_ & 7) << 4));
        const int rb1 = tb + 128 + (chlo ^ (((px_ + 1) & 7) << 4));
        const int rb2 = tb + 256 + (chlo ^ (((px_ + 2) & 7) << 4));
        const int rb3 = tb +       (chhi ^ ((px_ & 7) << 4));
        const int rb4 = tb + 128 + (chhi ^ (((px_ + 1) & 7) << 4));
        const int rb5 = tb + 256 + (chhi ^ (((px_ + 2) & 7) << 4));
        const float4 wt4 = *reinterpret_cast<const float4*>(wtc + (size_t)pc * KC + ch0);
        f32x4 ah = {0.f, 0.f, 0.f, 0.f};
        #pragma unroll
        for (int kt = 0; kt < 18; ++kt) {
          const int tap = kt >> 1, dy = tap / 3, dx = tap - dy * 3;
          const int base = (kt & 1) ? (dx == 0 ? rb3 : dx == 1 ? rb4 : rb5)
                                    : (dx == 0 ? rb0 : dx == 1 ? rb1 : rb2);
          const f16x8 bf = *reinterpret_cast<const f16x8*>(rhpadB + base + dy * 2048);
          ah = __builtin_amdgcn_mfma_f32_16x16x32_f16(afh[kt], bf, ah, 0, 0, 0);
        }
        if (act) {
          const float wta[4] = {wt4.x, wt4.y, wt4.z, wt4.w};
          const f16x4 zv = *reinterpret_cast<const f16x4*>(
              reinterpret_cast<const char*>(zbuf) + p * 128 + ((ch0 * 2) ^ ((p & 7) << 4)));
          const float4 hv = *reinterpret_cast<const float4*>(&h32[pc * 68 + ch0]);
          const float hva[4] = {hv.x, hv.y, hv.z, hv.w};
          f16x4 hw;
          float hna[4];
          #pragma unroll
          for (int jj = 0; jj < 4; ++jj) {
            float hh = tanhfast(ah[jj] + wta[jj]);
            float z = (float)zv[jj];
            float hn = hh + z * (hva[jj] - hh);   // (1-z)*hh + z*h
            hna[jj] = hn;
            hw[jj] = (_Float16)hn;
          }
          float4 hn4 = {hna[0], hna[1], hna[2], hna[3]};
          *reinterpret_cast<float4*>(&h32[pc * 68 + ch0]) = hn4;
          const int ppw = base0 + 17;
          *reinterpret_cast<f16x4*>(reinterpret_cast<char*>(hpad) +
              ppw * 128 + ((ch0 * 2) ^ ((ppw & 7) << 4))) = hw;
          *reinterpret_cast<f16x4*>(ad + (size_t)pc * KC + ch0) = hw;
        }
      }
    }
    __syncthreads();
  }
}

// ---------------------------------------------------------------------------
// softmax over K=64 per pixel-row; f16 in, f16 out (validated round 13).
// ---------------------------------------------------------------------------
__global__ __launch_bounds__(256)
void softmax_kernel(const _Float16* __restrict__ af, const _Float16* __restrict__ ab,
                    _Float16* __restrict__ out) {
  size_t idx = (size_t)blockIdx.x * 256 + threadIdx.x;   // 0..50175
  const _Float16* cf = af + idx * KC;
  const _Float16* cb = ab + idx * KC;
  _Float16* co = out + idx * KC;
  float v[KC];
  float mx = -3.4e38f;
  #pragma unroll
  for (int g = 0; g < 8; ++g) {
    f16x8 a = *reinterpret_cast<const f16x8*>(cf + g * 8);
    f16x8 bq = *reinterpret_cast<const f16x8*>(cb + g * 8);
    #pragma unroll
    for (int j = 0; j < 8; ++j) {
      float s = (float)a[j] + (float)bq[j];
      v[g * 8 + j] = s;
      mx = fmaxf(mx, s);
    }
  }
  float ssum = 0.0f;
  #pragma unroll
  for (int k = 0; k < KC; ++k) { v[k] = __expf(v[k] - mx); ssum += v[k]; }
  float inv = __builtin_amdgcn_rcpf(ssum);
  #pragma unroll
  for (int g = 0; g < 8; ++g) {
    f16x8 o;
    #pragma unroll
    for (int j = 0; j < 8; ++j) o[j] = (_Float16)(v[g * 8 + j] * inv);
    *reinterpret_cast<f16x8*>(co + g * 8) = o;
  }
}

// ---------------------------------------------------------------------------
// S[b][k] = sum over (t,p) of assign (f16 [n][p][k]). grid (8 seg, 8 b).
// ---------------------------------------------------------------------------
__global__ __launch_bounds__(256)
void sreduce_kernel(const _Float16* __restrict__ a, float* __restrict__ S) {
  __shared__ float red[4][64];
  const int seg = blockIdx.x, b = blockIdx.y, tid = threadIdx.x;
  const int k = tid & 63, rg = tid >> 6;
  const _Float16* base = a + (size_t)b * T_STEPS * HW * KC;
  float sum = 0.0f;
  for (int rr = seg * 784 + rg; rr < (seg + 1) * 784; rr += 4)
    sum += (float)base[(size_t)rr * KC + k];
  red[rg][k] = sum;
  __syncthreads();
  if (tid < 64) {
    float s = red[0][k] + red[1][k] + red[2][k] + red[3][k];
    atomicAdd(&S[b * KC + k], s);
  }
}

// ---------------------------------------------------------------------------
// VLAD GEMM partials (validated round 13). grid (8 d, 8 tc, 8 b).
// ---------------------------------------------------------------------------
__global__ __launch_bounds__(256)
void vlad_gemm_kernel(const _Float16* __restrict__ a, const _Float16* __restrict__ xrh,
                      float* __restrict__ Gpart) {
  __shared__ float sA[16][68];
  __shared__ float sX[16][68];
  const int tid = threadIdx.x;
  const int tx = tid & 15, ty = tid >> 4;
  const int d0 = blockIdx.x * 64;
  const int tc = blockIdx.y;
  const int b  = blockIdx.z;
  const int kk = tid & 63, pj = tid >> 6;
  float acc[4][4] = {};

  for (int tt = 0; tt < 4; ++tt) {
    int n = b * T_STEPS + tc * 4 + tt;
    const _Float16* an = a + (size_t)n * HW * KC;
    const _Float16* xn = xrh + (size_t)n * HW * DD;
    for (int p0 = 0; p0 < HW; p0 += 16) {
      __syncthreads();
      #pragma unroll
      for (int j = 0; j < 4; ++j) {
        int pl = pj * 4 + j;
        int p = p0 + pl;
        sA[pl][kk] = (p < HW) ? (float)an[(size_t)p * KC + kk] : 0.0f;
        sX[pl][kk] = (p < HW) ? (float)xn[(size_t)p * DD + d0 + kk] : 0.0f;
      }
      __syncthreads();
      #pragma unroll
      for (int pp = 0; pp < 16; ++pp) {
        float4 av = *reinterpret_cast<const float4*>(&sA[pp][ty * 4]);
        float4 xv = *reinterpret_cast<const float4*>(&sX[pp][tx * 4]);
        float aa[4] = {av.x, av.y, av.z, av.w};
        float xx[4] = {xv.x, xv.y, xv.z, xv.w};
        #pragma unroll
        for (int i = 0; i < 4; ++i)
          #pragma unroll
          for (int j = 0; j < 4; ++j)
            acc[i][j] += aa[i] * xx[j];
      }
    }
  }
  float* gp = Gpart + ((size_t)(tc * NB + b) * KC) * DD;
  #pragma unroll
  for (int i = 0; i < 4; ++i)
    #pragma unroll
    for (int j = 0; j < 4; ++j)
      gp[(ty * 4 + i) * DD + d0 + tx * 4 + j] = acc[i][j];
}

__global__ __launch_bounds__(256)
void finalize1_kernel(const float* __restrict__ Gpart, const float* __restrict__ S,
                      const float* __restrict__ centers, float* __restrict__ out,
                      float* __restrict__ bsum) {
  __shared__ float red[256];
  const int k = blockIdx.x, b = blockIdx.y, tid = threadIdx.x;
  const float sv = S[b * KC + k];
  float vals[2];
  float ss = 0.0f;
  #pragma unroll
  for (int r = 0; r < 2; ++r) {
    int d = tid + r * 256;
    float g = 0.0f;
    #pragma unroll
    for (int tc = 0; tc < 8; ++tc)
      g += Gpart[((size_t)(tc * NB + b) * KC + k) * DD + d];
    float v = g - sv * centers[k * DD + d];
    vals[r] = v; ss += v * v;
  }
  red[tid] = ss; __syncthreads();
  for (int st = 128; st > 0; st >>= 1) {
    if (tid < st) red[tid] += red[tid + st];
    __syncthreads();
  }
  float tot = red[0];
  float inv = 1.0f / fmaxf(sqrtf(tot), 1e-12f);
  #pragma unroll
  for (int r = 0; r < 2; ++r) {
    int d = tid + r * 256;
    out[(size_t)b * KC * DD + k * DD + d] = vals[r] * inv;
  }
  if (tid == 0) atomicAdd(&bsum[b], tot * inv * inv);
}

__global__ __launch_bounds__(256)
void finalize2_kernel(float* __restrict__ out, const float* __restrict__ bsum) {
  int idx = blockIdx.x * 256 + threadIdx.x;
  int b = idx >> 15;
  out[idx] = out[idx] / fmaxf(sqrtf(bsum[b]), 1e-12f);
}

// ---------------------------------------------------------------------------
extern "C" void kernel_launch(void* const* d_in, const int* in_sizes, int n_in,
                              void* d_out, int out_size, void* d_ws, size_t ws_size,
                              hipStream_t stream) {
  const float* x       = (const float*)d_in[0];
  const float* redu_w  = (const float*)d_in[1];
  const float* redu_b  = (const float*)d_in[2];
  const float* share_w = (const float*)d_in[3];
  const float* share_b = (const float*)d_in[4];
  const float* Uz      = (const float*)d_in[5];
  const float* Ur      = (const float*)d_in[6];
  const float* Uh      = (const float*)d_in[7];
  const float* centers = (const float*)d_in[8];
  float* out = (float*)d_out;

  // workspace layout (unchanged footprint vs rounds 4-13, ~172 MB):
  float* wxbc = (float*)d_ws;                                // [col][64] f32 (12.85MB)
  _Float16* assignh = (_Float16*)wxbc;                       // f16 overlay (wxbc dead after GRU)
  _Float16* xh = (_Float16*)(wxbc + (size_t)NCOL * KC);      // [col][1024] f16 (102.8MB)
  _Float16* a_f = xh;                                        // overlay (xh dead after gemmA)
  _Float16* a_b = a_f + (size_t)NFR * HW * KC;
  float* Gpart = (float*)(a_b + (size_t)NFR * HW * KC);      // 8*NB*KC*DD f32 (8.4MB)
  _Float16* xrh = xh + (size_t)NCOL * CIN;                   // [col][512] f16 (51.4MB)
  float* S = (float*)(xrh + (size_t)NCOL * DD);              // 512
  float* bsum = S + 512;                                     // 8
  _Float16* ufmt = (_Float16*)(bsum + 8);                    // 216*512 f16
  _Float16* wh = ufmt + 216 * 512;
  _Float16* swh = wh + (size_t)DD * CIN;

  hipMemsetAsync(bsum, 0, NB * sizeof(float), stream);
  hipMemsetAsync(S, 0, 512 * sizeof(float), stream);

  cvt_f16<<<dim3(512), 256, 0, stream>>>(redu_w, wh, DD * CIN);
  cvt_f16<<<dim3(32), 256, 0, stream>>>(share_w, swh, KC * DD);
  format_u<<<dim3(216), 64, 0, stream>>>(Uz, Ur, Uh, ufmt);
  transpose_x<<<dim3(16, 256), 256, 0, stream>>>(x, xh);

  // stage A: xrh[col][512] f16 = wh[512x1024] * xh^T
  gemm16<128, 4, true><<<dim3(392 * 4), 256, 0, stream>>>(
      wh, xh, redu_b, nullptr, xrh, DD, CIN);
  // stage B: wxbc[col][64] f32 = swh[64x512] * xrh^T
  gemm16<64, 1, false><<<dim3(392), 256, 0, stream>>>(
      swh, xrh, share_b, wxbc, nullptr, KC, DD);

  // GRU: round-10/13 proven kernel (443 us)
  gru_mfma8<<<dim3(16), 512, 0, stream>>>(wxbc, ufmt, a_f, a_b);

  softmax_kernel<<<dim3(196), 256, 0, stream>>>(a_f, a_b, assignh);
  sreduce_kernel<<<dim3(8, 8), 256, 0, stream>>>(assignh, S);
  vlad_gemm_kernel<<<dim3(8, 8, 8), 256, 0, stream>>>(assignh, xrh, Gpart);
  finalize1_kernel<<<dim3(64, 8), 256, 0, stream>>>(Gpart, S, centers, out, bsum);
  finalize2_kernel<<<dim3(1024), 256, 0, stream>>>(out, bsum);
}

// Round 17
// 770.205 us; speedup vs baseline: 1.9495x; 1.0012x over previous
//
#include <hip/hip_runtime.h>

#define HW 196
#define WIDTH 14
#define T_STEPS 32
#define KC 64      // centers / GRU channels
#define DD 512     // reduced dim
#define CIN 1024
#define NFR 256    // B*T
#define NB 8       // videos
#define NCOL (NFR * HW)   // 50176

using f16x8 = __attribute__((ext_vector_type(8))) _Float16;
using f16x4 = __attribute__((ext_vector_type(4))) _Float16;
using f32x4 = __attribute__((ext_vector_type(4))) float;

__device__ __forceinline__ void gload_lds16(const void* g, void* l) {
  __builtin_amdgcn_global_load_lds(
      (const __attribute__((address_space(1))) void*)g,
      (__attribute__((address_space(3))) void*)l, 16, 0, 0);
}

// fast sigmoid / tanh: v_exp_f32 + v_rcp_f32 (validated rounds 7-15).
__device__ __forceinline__ float sigf(float x) {
  return __builtin_amdgcn_rcpf(1.0f + __expf(-x));
}
__device__ __forceinline__ float tanhfast(float x) {
  float e = __expf(2.0f * x);
  return 1.0f - 2.0f * __builtin_amdgcn_rcpf(e + 1.0f);
}

// ---------------------------------------------------------------------------
// Fused prep: blocks 0..511 convert redu_w (f32->f16), 512..543 convert
// share_w, 544..597 pre-format U into 16x16x32 MFMA A-fragments (4 frags
// per block, 64-lane groups; math identical to validated format_u).
// ---------------------------------------------------------------------------
__global__ __launch_bounds__(256)
void prep_kernel(const float* __restrict__ redu_w, const float* __restrict__ share_w,
                 const float* __restrict__ Uz, const float* __restrict__ Ur,
                 const float* __restrict__ Uh, _Float16* __restrict__ wh,
                 _Float16* __restrict__ swh, _Float16* __restrict__ ufmt) {
  const int bx = blockIdx.x;
  const int tid = threadIdx.x;
  if (bx < 544) {
    const float* src = (bx < 512) ? redu_w : share_w;
    _Float16* dst = (bx < 512) ? wh : swh;
    const int i = ((bx < 512) ? bx : (bx - 512)) * 1024 + tid * 4;
    float4 v = *reinterpret_cast<const float4*>(src + i);
    f16x4 o;
    o[0] = (_Float16)v.x; o[1] = (_Float16)v.y;
    o[2] = (_Float16)v.z; o[3] = (_Float16)v.w;
    *reinterpret_cast<f16x4*>(dst + i) = o;
    return;
  }
  // format_u section: f = 0..215
  const int f = (bx - 544) * 4 + (tid >> 6);
  const int lane = tid & 63;
  const int l16 = lane & 15;
  const float* U;
  int ch, kt;
  if (f < 144) {
    int pair = f / 36, rem = f - pair * 36;
    int mi = rem / 18; kt = rem - mi * 18;
    U = (pair < 2) ? Uz : Ur;
    ch = (pair & 1) * 32 + mi * 16 + l16;
  } else {
    int g = f - 144;
    int pair = g / 36, rem = g - pair * 36;
    int mi = rem / 18; kt = rem - mi * 18;
    U = Uh;
    ch = pair * 32 + mi * 16 + l16;
  }
  const int tap = kt >> 1;
  const int k0 = (kt & 1) * 32 + (lane >> 4) * 8;
  f16x8 v;
  #pragma unroll
  for (int j = 0; j < 8; ++j)
    v[j] = (_Float16)U[(size_t)ch * 576 + (k0 + j) * 9 + tap];
  *reinterpret_cast<f16x8*>(ufmt + (size_t)f * 512 + lane * 8) = v;
}

// ---------------------------------------------------------------------------
// Transpose-convert x: (n, c, p) f32 -> xh[(n*196+p)][c] f16.
// ---------------------------------------------------------------------------
__global__ __launch_bounds__(256)
void transpose_x(const float* __restrict__ x, _Float16* __restrict__ xh) {
  __shared__ float tile[64][197];
  const int tid = threadIdx.x;
  const int w = tid >> 6, lane = tid & 63;
  const int n = blockIdx.y;
  const int c0 = blockIdx.x * 64;
  const float* src = x + ((size_t)n * CIN + c0) * HW;
  for (int rr = 0; rr < 16; ++rr) {
    int c = w * 16 + rr;
    if (lane < 49) {
      float4 v = *reinterpret_cast<const float4*>(src + (size_t)c * HW + lane * 4);
      tile[c][lane * 4 + 0] = v.x; tile[c][lane * 4 + 1] = v.y;
      tile[c][lane * 4 + 2] = v.z; tile[c][lane * 4 + 3] = v.w;
    }
  }
  __syncthreads();
  _Float16* dst = xh + (size_t)n * HW * CIN + c0;
  #pragma unroll
  for (int pass = 0; pass < 13; ++pass) {
    int p = (tid >> 4) + pass * 16;
    int cg = (tid & 15) * 4;
    if (p < HW) {
      f16x4 v;
      #pragma unroll
      for (int j = 0; j < 4; ++j) v[j] = (_Float16)tile[cg + j][p];
      *reinterpret_cast<f16x4*>(dst + (size_t)p * CIN + cg) = v;
    }
  }
}

// ---------------------------------------------------------------------------
// f16 MFMA GEMM (validated rounds 4-15).
// ---------------------------------------------------------------------------
template<int BM, int NMT, bool WT>
__global__ __launch_bounds__(256)
void gemm16(const _Float16* __restrict__ A, const _Float16* __restrict__ Bmat,
            const float* __restrict__ bias, float* __restrict__ outC,
            _Float16* __restrict__ outT, int M, int K) {
  constexpr int MF = BM / 32;
  union Smem {
    struct { _Float16 a[BM * 64]; _Float16 b[128 * 64]; } s;
    _Float16 t[WT ? 128 * 132 : 1];
  };
  __shared__ Smem u;

  const int tid = threadIdx.x;
  const int lane = tid & 63;
  const int w = tid >> 6;
  const int wm = w >> 1, wn = w & 1;
  const int l16 = lane & 15, lhi = lane >> 4;
  const int srow = lane >> 3, sslot = lane & 7;
  const int swz = (sslot ^ srow) << 4;
  const int nct = gridDim.x / NMT;
  const int mt = blockIdx.x / nct;
  const int ct = blockIdx.x - mt * nct;
  const int m0 = mt * BM;
  const int col0 = ct * 128;

  f32x4 acc[MF][4];
  #pragma unroll
  for (int i = 0; i < MF; ++i)
    #pragma unroll
    for (int f = 0; f < 4; ++f) acc[i][f] = {0.f, 0.f, 0.f, 0.f};

  for (int k0 = 0; k0 < K; k0 += 64) {
    #pragma unroll
    for (int s = 0; s < BM / 32; ++s) {
      int r = w * (BM / 4) + s * 8;
      gload_lds16((const char*)(A + (size_t)(m0 + r + srow) * K + k0) + swz,
                  (char*)u.s.a + r * 128);
    }
    #pragma unroll
    for (int s = 0; s < 4; ++s) {
      int r = w * 32 + s * 8;
      gload_lds16((const char*)(Bmat + (size_t)(col0 + r + srow) * K + k0) + swz,
                  (char*)u.s.b + r * 128);
    }
    __syncthreads();
    #pragma unroll
    for (int kk = 0; kk < 2; ++kk) {
      f16x8 af[MF];
      #pragma unroll
      for (int i = 0; i < MF; ++i) {
        int row = wm * (MF * 16) + i * 16 + l16;
        af[i] = *reinterpret_cast<const f16x8*>(
            (const char*)u.s.a + row * 128 + ((kk * 64 + lhi * 16) ^ ((row & 7) << 4)));
      }
      #pragma unroll
      for (int f = 0; f < 4; ++f) {
        int row = wn * 64 + f * 16 + l16;
        f16x8 bf = *reinterpret_cast<const f16x8*>(
            (const char*)u.s.b + row * 128 + ((kk * 64 + lhi * 16) ^ ((row & 7) << 4)));
        #pragma unroll
        for (int i = 0; i < MF; ++i)
          acc[i][f] = __builtin_amdgcn_mfma_f32_16x16x32_f16(af[i], bf, acc[i][f], 0, 0, 0);
      }
    }
    __syncthreads();
  }

  if constexpr (!WT) {
    #pragma unroll
    for (int i = 0; i < MF; ++i) {
      int m = m0 + wm * (MF * 16) + i * 16 + lhi * 4;
      float b0 = bias[m], b1 = bias[m + 1], b2 = bias[m + 2], b3 = bias[m + 3];
      #pragma unroll
      for (int f = 0; f < 4; ++f) {
        int col = col0 + wn * 64 + f * 16 + l16;
        float4 o = {acc[i][f][0] + b0, acc[i][f][1] + b1,
                    acc[i][f][2] + b2, acc[i][f][3] + b3};
        *reinterpret_cast<float4*>(outC + (size_t)col * M + m) = o;
      }
    }
  } else {
    #pragma unroll
    for (int i = 0; i < MF; ++i) {
      int ml = wm * (MF * 16) + i * 16 + lhi * 4;
      int m = m0 + ml;
      float b0 = bias[m], b1 = bias[m + 1], b2 = bias[m + 2], b3 = bias[m + 3];
      #pragma unroll
      for (int f = 0; f < 4; ++f) {
        int cl = wn * 64 + f * 16 + l16;
        f16x4 v;
        v[0] = (_Float16)(acc[i][f][0] + b0);
        v[1] = (_Float16)(acc[i][f][1] + b1);
        v[2] = (_Float16)(acc[i][f][2] + b2);
        v[3] = (_Float16)(acc[i][f][3] + b3);
        *reinterpret_cast<f16x4*>((char*)u.t + cl * 264 + ml * 2) = v;
      }
    }
    __syncthreads();
    #pragma unroll
    for (int pass = 0; pass < 16; ++pass) {
      int row = (tid >> 5) + pass * 8;
      int coff = (tid & 31) * 4;
      f16x4 v = *reinterpret_cast<const f16x4*>((const char*)u.t + row * 264 + coff * 2);
      *reinterpret_cast<f16x4*>(outT + (size_t)(col0 + row) * M + m0 + coff) = v;
    }
  }
}

// ---------------------------------------------------------------------------
// GRU (EXACT round-10/13/15 kernel, proven 443 us, best of 8 structural
// variants). Hard constraints established this session:
//  - 512-thr block (1024 thr -> 64-VGPR cap, catastrophic spill, r9)
//  - af fragment arrays HOISTED per phase, <=2 streams (r11/r14)
//  - z/h state in LDS, not registers (persistent reg state -> spill, r7-9)
//  - 16x16x32 MFMA (32x32x16 doubles acc VGPRs -> spill + dep chains, r14)
// ---------------------------------------------------------------------------
__global__ __launch_bounds__(512, 2)
void gru_mfma8(const float* __restrict__ wxbc, const _Float16* __restrict__ ufmt,
               _Float16* __restrict__ a_f, _Float16* __restrict__ a_b) {
  __shared__ __align__(16) _Float16 hpad[256 * 64];   // 32KB padded h (swizzled)
  __shared__ __align__(16) _Float16 rhpad[256 * 64];  // 32KB padded r*h
  __shared__ __align__(16) _Float16 zbuf[208 * 64];   // 26.6KB z (swizzled)
  __shared__ __align__(16) float h32[HW * 68];        // 52KB fp32 h, padded rows

  const int tid = threadIdx.x;
  const int lane = tid & 63;
  const int w = tid >> 6;            // wave 0..7
  const int l16 = lane & 15, lhi = lane >> 4;
  const int chain = blockIdx.x;
  const int b = chain >> 1, dir = chain & 1;
  const int mi = w & 3;
  const int half = w >> 2;
  const int ntb = half * 7;          // base pixel-tile
  const int ntn = half ? 6 : 7;      // tiles owned
  const int ch0 = mi * 16 + lhi * 4;
  const int chlo = lhi * 16, chhi = 64 + lhi * 16;

  for (int i = tid; i < 256 * 64; i += 512) { hpad[i] = (_Float16)0.f; rhpad[i] = (_Float16)0.f; }
  for (int i = tid; i < HW * 68; i += 512) h32[i] = 0.0f;
  __syncthreads();

  _Float16* adest = dir ? a_b : a_f;
  const char* hpadB = reinterpret_cast<const char*>(hpad);
  const char* rhpadB = reinterpret_cast<const char*>(rhpad);
  const _Float16* uf = ufmt + (size_t)lane * 8;
  const int fz0 = (mi >> 1) * 36 + (mi & 1) * 18;

  for (int t = 0; t < T_STEPS; ++t) {
    const int tw = dir ? (T_STEPS - 1 - t) : t;
    const float* wtc = wxbc + (size_t)(b * T_STEPS + tw) * HW * KC;

    // ================= phase 1: z -> zbuf, r*h -> rhpad ====================
    {
      f16x8 afz[18], afr[18];
      #pragma unroll
      for (int kt = 0; kt < 18; ++kt) {
        afz[kt] = *reinterpret_cast<const f16x8*>(uf + (size_t)(fz0 + kt) * 512);
        afr[kt] = *reinterpret_cast<const f16x8*>(uf + (size_t)(fz0 + 72 + kt) * 512);
      }
      for (int i = 0; i < ntn; ++i) {
        const int nt = ntb + i;
        const int p = nt * 16 + l16;
        const bool act = p < HW;
        const int pc = act ? p : (HW - 1);
        const int py = pc / 14, px_ = pc - py * 14;
        const int base0 = py * 16 + px_;
        const int tb = base0 * 128;
        const int rb0 = tb +       (chlo ^ ((px_ & 7) << 4));
        const int rb1 = tb + 128 + (chlo ^ (((px_ + 1) & 7) << 4));
        const int rb2 = tb + 256 + (chlo ^ (((px_ + 2) & 7) << 4));
        const int rb3 = tb +       (chhi ^ ((px_ & 7) << 4));
        const int rb4 = tb + 128 + (chhi ^ (((px_ + 1) & 7) << 4));
        const int rb5 = tb + 256 + (chhi ^ (((px_ + 2) & 7) << 4));
        const float4 wt4 = *reinterpret_cast<const float4*>(wtc + (size_t)pc * KC + ch0);
        f32x4 az = {0.f, 0.f, 0.f, 0.f};
        f32x4 ar = {0.f, 0.f, 0.f, 0.f};
        #pragma unroll
        for (int kt = 0; kt < 18; ++kt) {
          const int tap = kt >> 1, dy = tap / 3, dx = tap - dy * 3;
          const int base = (kt & 1) ? (dx == 0 ? rb3 : dx == 1 ? rb4 : rb5)
                                    : (dx == 0 ? rb0 : dx == 1 ? rb1 : rb2);
          const f16x8 bf = *reinterpret_cast<const f16x8*>(hpadB + base + dy * 2048);
          az = __builtin_amdgcn_mfma_f32_16x16x32_f16(afz[kt], bf, az, 0, 0, 0);
          ar = __builtin_amdgcn_mfma_f32_16x16x32_f16(afr[kt], bf, ar, 0, 0, 0);
        }
        if (act) {
          const float wta[4] = {wt4.x, wt4.y, wt4.z, wt4.w};
          const float4 hv = *reinterpret_cast<const float4*>(&h32[pc * 68 + ch0]);
          const float hva[4] = {hv.x, hv.y, hv.z, hv.w};
          f16x4 zw, rhw;
          #pragma unroll
          for (int jj = 0; jj < 4; ++jj) {
            float z = sigf(az[jj] + wta[jj]);
            float r = sigf(ar[jj] + wta[jj]);
            zw[jj] = (_Float16)z;
            rhw[jj] = (_Float16)(r * hva[jj]);
          }
          *reinterpret_cast<f16x4*>(reinterpret_cast<char*>(zbuf) +
              p * 128 + ((ch0 * 2) ^ ((p & 7) << 4))) = zw;
          const int ppw = base0 + 17;
          *reinterpret_cast<f16x4*>(reinterpret_cast<char*>(rhpad) +
              ppw * 128 + ((ch0 * 2) ^ ((ppw & 7) << 4))) = rhw;
        }
      }
    }
    __syncthreads();

    // ================= phase 2: hh = tanh(wt + conv(rh,Uh)); update h ======
    {
      _Float16* ad = adest + (size_t)(b * T_STEPS + tw) * HW * KC;
      f16x8 afh[18];
      #pragma unroll
      for (int kt = 0; kt < 18; ++kt)
        afh[kt] = *reinterpret_cast<const f16x8*>(uf + (size_t)(144 + fz0 + kt) * 512);
      for (int i = 0; i < ntn; ++i) {
        const int nt = ntb + i;
        const int p = nt * 16 + l16;
        const bool act = p < HW;
        const int pc = act ? p : (HW - 1);
        const int py = pc / 14, px_ = pc - py * 14;
        const int base0 = py * 16 + px_;
        const int tb = base0 * 128;
        const int rb0 = tb +       (chlo ^ ((px_ & 7) << 4));
        const int rb1 = tb + 128 + (chlo ^ (((px_ + 1) & 7) << 4));
        const int rb2 = tb + 256 + (chlo ^ (((px_ + 2) & 7) << 4));
        const int rb3 = tb +       (chhi ^ ((px_ & 7) << 4));
        const int rb4 = tb + 128 + (chhi ^ (((px_ + 1) & 7) << 4));
        const int rb5 = tb + 256 + (chhi ^ (((px_ + 2) & 7) << 4));
        const float4 wt4 = *reinterpret_cast<const float4*>(wtc + (size_t)pc * KC + ch0);
        f32x4 ah = {0.f, 0.f, 0.f, 0.f};
        #pragma unroll
        for (int kt = 0; kt < 18; ++kt) {
          const int tap = kt >> 1, dy = tap / 3, dx = tap - dy * 3;
          const int base = (kt & 1) ? (dx == 0 ? rb3 : dx == 1 ? rb4 : rb5)
                                    : (dx == 0 ? rb0 : dx == 1 ? rb1 : rb2);
          const f16x8 bf = *reinterpret_cast<const f16x8*>(rhpadB + base + dy * 2048);
          ah = __builtin_amdgcn_mfma_f32_16x16x32_f16(afh[kt], bf, ah, 0, 0, 0);
        }
        if (act) {
          const float wta[4] = {wt4.x, wt4.y, wt4.z, wt4.w};
          const f16x4 zv = *reinterpret_cast<const f16x4*>(
              reinterpret_cast<const char*>(zbuf) + p * 128 + ((ch0 * 2) ^ ((p & 7) << 4)));
          const float4 hv = *reinterpret_cast<const float4*>(&h32[pc * 68 + ch0]);
          const float hva[4] = {hv.x, hv.y, hv.z, hv.w};
          f16x4 hw;
          float hna[4];
          #pragma unroll
          for (int jj = 0; jj < 4; ++jj) {
            float hh = tanhfast(ah[jj] + wta[jj]);
            float z = (float)zv[jj];
            float hn = hh + z * (hva[jj] - hh);   // (1-z)*hh + z*h
            hna[jj] = hn;
            hw[jj] = (_Float16)hn;
          }
          float4 hn4 = {hna[0], hna[1], hna[2], hna[3]};
          *reinterpret_cast<float4*>(&h32[pc * 68 + ch0]) = hn4;
          const int ppw = base0 + 17;
          *reinterpret_cast<f16x4*>(reinterpret_cast<char*>(hpad) +
              ppw * 128 + ((ch0 * 2) ^ ((ppw & 7) << 4))) = hw;
          *reinterpret_cast<f16x4*>(ad + (size_t)pc * KC + ch0) = hw;
        }
      }
    }
    __syncthreads();
  }
}

// ---------------------------------------------------------------------------
// softmax over K=64 per pixel-row; f16 in, f16 out (validated round 13).
// ---------------------------------------------------------------------------
__global__ __launch_bounds__(256)
void softmax_kernel(const _Float16* __restrict__ af, const _Float16* __restrict__ ab,
                    _Float16* __restrict__ out) {
  size_t idx = (size_t)blockIdx.x * 256 + threadIdx.x;   // 0..50175
  const _Float16* cf = af + idx * KC;
  const _Float16* cb = ab + idx * KC;
  _Float16* co = out + idx * KC;
  float v[KC];
  float mx = -3.4e38f;
  #pragma unroll
  for (int g = 0; g < 8; ++g) {
    f16x8 a = *reinterpret_cast<const f16x8*>(cf + g * 8);
    f16x8 bq = *reinterpret_cast<const f16x8*>(cb + g * 8);
    #pragma unroll
    for (int j = 0; j < 8; ++j) {
      float s = (float)a[j] + (float)bq[j];
      v[g * 8 + j] = s;
      mx = fmaxf(mx, s);
    }
  }
  float ssum = 0.0f;
  #pragma unroll
  for (int k = 0; k < KC; ++k) { v[k] = __expf(v[k] - mx); ssum += v[k]; }
  float inv = __builtin_amdgcn_rcpf(ssum);
  #pragma unroll
  for (int g = 0; g < 8; ++g) {
    f16x8 o;
    #pragma unroll
    for (int j = 0; j < 8; ++j) o[j] = (_Float16)(v[g * 8 + j] * inv);
    *reinterpret_cast<f16x8*>(co + g * 8) = o;
  }
}

// ---------------------------------------------------------------------------
// S[b][k] = sum over (t,p) of assign (f16 [n][p][k]). grid (8 seg, 8 b).
// ---------------------------------------------------------------------------
__global__ __launch_bounds__(256)
void sreduce_kernel(const _Float16* __restrict__ a, float* __restrict__ S) {
  __shared__ float red[4][64];
  const int seg = blockIdx.x, b = blockIdx.y, tid = threadIdx.x;
  const int k = tid & 63, rg = tid >> 6;
  const _Float16* base = a + (size_t)b * T_STEPS * HW * KC;
  float sum = 0.0f;
  for (int rr = seg * 784 + rg; rr < (seg + 1) * 784; rr += 4)
    sum += (float)base[(size_t)rr * KC + k];
  red[rg][k] = sum;
  __syncthreads();
  if (tid < 64) {
    float s = red[0][k] + red[1][k] + red[2][k] + red[3][k];
    atomicAdd(&S[b * KC + k], s);
  }
}

// ---------------------------------------------------------------------------
// VLAD GEMM partials (validated round 13). grid (8 d, 8 tc, 8 b).
// ---------------------------------------------------------------------------
__global__ __launch_bounds__(256)
void vlad_gemm_kernel(const _Float16* __restrict__ a, const _Float16* __restrict__ xrh,
                      float* __restrict__ Gpart) {
  __shared__ float sA[16][68];
  __shared__ float sX[16][68];
  const int tid = threadIdx.x;
  const int tx = tid & 15, ty = tid >> 4;
  const int d0 = blockIdx.x * 64;
  const int tc = blockIdx.y;
  const int b  = blockIdx.z;
  const int kk = tid & 63, pj = tid >> 6;
  float acc[4][4] = {};

  for (int tt = 0; tt < 4; ++tt) {
    int n = b * T_STEPS + tc * 4 + tt;
    const _Float16* an = a + (size_t)n * HW * KC;
    const _Float16* xn = xrh + (size_t)n * HW * DD;
    for (int p0 = 0; p0 < HW; p0 += 16) {
      __syncthreads();
      #pragma unroll
      for (int j = 0; j < 4; ++j) {
        int pl = pj * 4 + j;
        int p = p0 + pl;
        sA[pl][kk] = (p < HW) ? (float)an[(size_t)p * KC + kk] : 0.0f;
        sX[pl][kk] = (p < HW) ? (float)xn[(size_t)p * DD + d0 + kk] : 0.0f;
      }
      __syncthreads();
      #pragma unroll
      for (int pp = 0; pp < 16; ++pp) {
        float4 av = *reinterpret_cast<const float4*>(&sA[pp][ty * 4]);
        float4 xv = *reinterpret_cast<const float4*>(&sX[pp][tx * 4]);
        float aa[4] = {av.x, av.y, av.z, av.w};
        float xx[4] = {xv.x, xv.y, xv.z, xv.w};
        #pragma unroll
        for (int i = 0; i < 4; ++i)
          #pragma unroll
          for (int j = 0; j < 4; ++j)
            acc[i][j] += aa[i] * xx[j];
      }
    }
  }
  float* gp = Gpart + ((size_t)(tc * NB + b) * KC) * DD;
  #pragma unroll
  for (int i = 0; i < 4; ++i)
    #pragma unroll
    for (int j = 0; j < 4; ++j)
      gp[(ty * 4 + i) * DD + d0 + tx * 4 + j] = acc[i][j];
}

__global__ __launch_bounds__(256)
void finalize1_kernel(const float* __restrict__ Gpart, const float* __restrict__ S,
                      const float* __restrict__ centers, float* __restrict__ out,
                      float* __restrict__ bsum) {
  __shared__ float red[256];
  const int k = blockIdx.x, b = blockIdx.y, tid = threadIdx.x;
  const float sv = S[b * KC + k];
  float vals[2];
  float ss = 0.0f;
  #pragma unroll
  for (int r = 0; r < 2; ++r) {
    int d = tid + r * 256;
    float g = 0.0f;
    #pragma unroll
    for (int tc = 0; tc < 8; ++tc)
      g += Gpart[((size_t)(tc * NB + b) * KC + k) * DD + d];
    float v = g - sv * centers[k * DD + d];
    vals[r] = v; ss += v * v;
  }
  red[tid] = ss; __syncthreads();
  for (int st = 128; st > 0; st >>= 1) {
    if (tid < st) red[tid] += red[tid + st];
    __syncthreads();
  }
  float tot = red[0];
  float inv = 1.0f / fmaxf(sqrtf(tot), 1e-12f);
  #pragma unroll
  for (int r = 0; r < 2; ++r) {
    int d = tid + r * 256;
    out[(size_t)b * KC * DD + k * DD + d] = vals[r] * inv;
  }
  if (tid == 0) atomicAdd(&bsum[b], tot * inv * inv);
}

__global__ __launch_bounds__(256)
void finalize2_kernel(float* __restrict__ out, const float* __restrict__ bsum) {
  int idx = blockIdx.x * 256 + threadIdx.x;
  int b = idx >> 15;
  out[idx] = out[idx] / fmaxf(sqrtf(bsum[b]), 1e-12f);
}

// ---------------------------------------------------------------------------
extern "C" void kernel_launch(void* const* d_in, const int* in_sizes, int n_in,
                              void* d_out, int out_size, void* d_ws, size_t ws_size,
                              hipStream_t stream) {
  const float* x       = (const float*)d_in[0];
  const float* redu_w  = (const float*)d_in[1];
  const float* redu_b  = (const float*)d_in[2];
  const float* share_w = (const float*)d_in[3];
  const float* share_b = (const float*)d_in[4];
  const float* Uz      = (const float*)d_in[5];
  const float* Ur      = (const float*)d_in[6];
  const float* Uh      = (const float*)d_in[7];
  const float* centers = (const float*)d_in[8];
  float* out = (float*)d_out;

  // workspace layout (unchanged footprint vs rounds 4-15, ~172 MB):
  float* wxbc = (float*)d_ws;                                // [col][64] f32 (12.85MB)
  _Float16* assignh = (_Float16*)wxbc;                       // f16 overlay (wxbc dead after GRU)
  _Float16* xh = (_Float16*)(wxbc + (size_t)NCOL * KC);      // [col][1024] f16 (102.8MB)
  _Float16* a_f = xh;                                        // overlay (xh dead after gemmA)
  _Float16* a_b = a_f + (size_t)NFR * HW * KC;
  float* Gpart = (float*)(a_b + (size_t)NFR * HW * KC);      // 8*NB*KC*DD f32 (8.4MB)
  _Float16* xrh = xh + (size_t)NCOL * CIN;                   // [col][512] f16 (51.4MB)
  float* S = (float*)(xrh + (size_t)NCOL * DD);              // 512
  float* bsum = S + 512;                                     // 8 (contiguous with S)
  _Float16* ufmt = (_Float16*)(bsum + 8);                    // 216*512 f16
  _Float16* wh = ufmt + 216 * 512;
  _Float16* swh = wh + (size_t)DD * CIN;

  // single memset covers S (512) + bsum (8), contiguous
  hipMemsetAsync(S, 0, 520 * sizeof(float), stream);

  // fused prep: weight converts + U fragment pre-format (1 launch vs 3)
  prep_kernel<<<dim3(598), 256, 0, stream>>>(redu_w, share_w, Uz, Ur, Uh,
                                             wh, swh, ufmt);
  transpose_x<<<dim3(16, 256), 256, 0, stream>>>(x, xh);

  // stage A: xrh[col][512] f16 = wh[512x1024] * xh^T
  gemm16<128, 4, true><<<dim3(392 * 4), 256, 0, stream>>>(
      wh, xh, redu_b, nullptr, xrh, DD, CIN);
  // stage B: wxbc[col][64] f32 = swh[64x512] * xrh^T
  gemm16<64, 1, false><<<dim3(392), 256, 0, stream>>>(
      swh, xrh, share_b, wxbc, nullptr, KC, DD);

  // GRU: round-10/13/15 proven kernel (443 us)
  gru_mfma8<<<dim3(16), 512, 0, stream>>>(wxbc, ufmt, a_f, a_b);

  softmax_kernel<<<dim3(196), 256, 0, stream>>>(a_f, a_b, assignh);
  sreduce_kernel<<<dim3(8, 8), 256, 0, stream>>>(assignh, S);
  vlad_gemm_kernel<<<dim3(8, 8, 8), 256, 0, stream>>>(assignh, xrh, Gpart);
  finalize1_kernel<<<dim3(64, 8), 256, 0, stream>>>(Gpart, S, centers, out, bsum);
  finalize2_kernel<<<dim3(1024), 256, 0, stream>>>(out, bsum);
}